// Round 1
// baseline (369.145 us; speedup 1.0000x reference)
//
#include <hip/hip_runtime.h>

// Per-edge cosine similarity on concat([x,h]) features, D=64 per array (128 total).
// Kernel 1: per-node inverse L2 norm (one wave per node).
// Kernel 2: per-edge dot * inv_norms (16 lanes per edge, float4 gathers).

#define FD 64  // feature dim per array

__global__ void norm_kernel(const float* __restrict__ xd, const float* __restrict__ hd,
                            const float* __restrict__ xg, const float* __restrict__ hg,
                            float* __restrict__ inv_nd, float* __restrict__ inv_ng,
                            int n_d, int n_g)
{
    int wave = (int)((blockIdx.x * blockDim.x + threadIdx.x) >> 6);
    int lane = threadIdx.x & 63;
    int total = n_d + n_g;
    if (wave >= total) return;

    const float* x; const float* h; float* o; int n;
    if (wave < n_d) { x = xd; h = hd; o = inv_nd; n = wave; }
    else            { x = xg; h = hg; o = inv_ng; n = wave - n_d; }

    float v = x[(size_t)n * FD + lane];
    float w = h[(size_t)n * FD + lane];
    float ss = v * v + w * w;

    #pragma unroll
    for (int m = 32; m >= 1; m >>= 1) ss += __shfl_xor(ss, m);

    if (lane == 0) o[n] = rsqrtf(ss);
}

// 16 lanes per edge. Each lane loads one float4 from each of the 4 feature
// arrays (16 float4 per 64-float row). Reduce over the 16-lane group.
__global__ void edge_kernel(const float4* __restrict__ xd, const float4* __restrict__ hd,
                            const float4* __restrict__ xg, const float4* __restrict__ hg,
                            const int* __restrict__ src, const int* __restrict__ dst,
                            const float* __restrict__ inv_nd, const float* __restrict__ inv_ng,
                            float* __restrict__ out, int n_edges)
{
    int tid  = (int)(blockIdx.x * blockDim.x + threadIdx.x);
    int lane = threadIdx.x & 15;
    int e    = tid >> 4;
    if (e >= n_edges) return;

    int s = src[e];
    int d = dst[e];

    // 64 floats = 16 float4 per row
    float4 a  = xd[(size_t)s * 16 + lane];
    float4 b  = xg[(size_t)d * 16 + lane];
    float4 c  = hd[(size_t)s * 16 + lane];
    float4 g4 = hg[(size_t)d * 16 + lane];

    float p = a.x * b.x + a.y * b.y + a.z * b.z + a.w * b.w
            + c.x * g4.x + c.y * g4.y + c.z * g4.z + c.w * g4.w;

    // reduce over the 16-lane group (xor stays inside the group)
    p += __shfl_xor(p, 8);
    p += __shfl_xor(p, 4);
    p += __shfl_xor(p, 2);
    p += __shfl_xor(p, 1);

    if (lane == 0) out[e] = p * inv_nd[s] * inv_ng[d];
}

extern "C" void kernel_launch(void* const* d_in, const int* in_sizes, int n_in,
                              void* d_out, int out_size, void* d_ws, size_t ws_size,
                              hipStream_t stream) {
    const float* xd = (const float*)d_in[0];
    const float* hd = (const float*)d_in[1];
    const float* xg = (const float*)d_in[2];
    const float* hg = (const float*)d_in[3];
    const int*  src = (const int*)d_in[4];
    const int*  dst = (const int*)d_in[5];

    int n_d     = in_sizes[0] / FD;
    int n_g     = in_sizes[2] / FD;
    int n_edges = in_sizes[4];

    float* inv_nd = (float*)d_ws;
    float* inv_ng = inv_nd + n_d;
    float* out    = (float*)d_out;

    int total_nodes = n_d + n_g;
    int nb1 = (total_nodes * 64 + 255) / 256;   // one wave per node
    norm_kernel<<<nb1, 256, 0, stream>>>(xd, hd, xg, hg, inv_nd, inv_ng, n_d, n_g);

    int nb2 = (int)(((long long)n_edges * 16 + 255) / 256);  // 16 lanes per edge
    edge_kernel<<<nb2, 256, 0, stream>>>((const float4*)xd, (const float4*)hd,
                                         (const float4*)xg, (const float4*)hg,
                                         src, dst, inv_nd, inv_ng, out, n_edges);
}

// Round 2
// 231.910 us; speedup vs baseline: 1.5918x; 1.5918x over previous
//
#include <hip/hip_runtime.h>
#include <hip/hip_fp16.h>

// Per-edge cosine similarity on concat([x,h]) features, D=64 per array.
// Kernel 1 (pack): per node, compute r = rsqrt(||[x,h]||^2) and store the
//   normalized 128-dim vector as fp16 (256 B/row) in workspace, x/h interleaved.
// Kernel 2 (edge): 16 lanes/edge, each lane one float4 (8 halves) from each
//   of the two packed rows -> dot -> done. 512 B gathered per edge (was 1024+8).

#define FD 64  // feature dim per array

__global__ void pack_kernel(const float* __restrict__ xd, const float* __restrict__ hd,
                            const float* __restrict__ xg, const float* __restrict__ hg,
                            __half2* __restrict__ fd, __half2* __restrict__ fg,
                            int n_d, int n_g)
{
    int wave = (int)((blockIdx.x * blockDim.x + threadIdx.x) >> 6);
    int lane = threadIdx.x & 63;
    int total = n_d + n_g;
    if (wave >= total) return;

    const float* x; const float* h; __half2* o; int n;
    if (wave < n_d) { x = xd; h = hd; o = fd; n = wave; }
    else            { x = xg; h = hg; o = fg; n = wave - n_d; }

    float v = x[(size_t)n * FD + lane];
    float w = h[(size_t)n * FD + lane];
    float ss = v * v + w * w;

    #pragma unroll
    for (int m = 32; m >= 1; m >>= 1) ss += __shfl_xor(ss, m);
    // butterfly: every lane now holds the full sum
    float r = rsqrtf(ss);

    // interleaved layout: row element 2*lane = x[lane]*r, 2*lane+1 = h[lane]*r.
    // Same permutation for both node types -> dot is unchanged.
    o[(size_t)n * FD + lane] = __floats2half2_rn(v * r, w * r);
}

// 16 lanes per edge; packed row = 128 halves = 256 B = 16 float4.
__global__ void edge_kernel(const float4* __restrict__ fd, const float4* __restrict__ fg,
                            const int* __restrict__ src, const int* __restrict__ dst,
                            float* __restrict__ out, int n_edges)
{
    int tid  = (int)(blockIdx.x * blockDim.x + threadIdx.x);
    int lane = threadIdx.x & 15;
    int e    = tid >> 4;
    if (e >= n_edges) return;

    int s = src[e];
    int d = dst[e];

    float4 av = fd[(size_t)s * 16 + lane];
    float4 bv = fg[(size_t)d * 16 + lane];

    const __half2* ah = (const __half2*)&av;
    const __half2* bh = (const __half2*)&bv;

    float p = 0.f;
    #pragma unroll
    for (int i = 0; i < 4; ++i) {
        float2 a2 = __half22float2(ah[i]);
        float2 b2 = __half22float2(bh[i]);
        p += a2.x * b2.x + a2.y * b2.y;
    }

    p += __shfl_xor(p, 8);
    p += __shfl_xor(p, 4);
    p += __shfl_xor(p, 2);
    p += __shfl_xor(p, 1);

    if (lane == 0) out[e] = p;
}

extern "C" void kernel_launch(void* const* d_in, const int* in_sizes, int n_in,
                              void* d_out, int out_size, void* d_ws, size_t ws_size,
                              hipStream_t stream) {
    const float* xd = (const float*)d_in[0];
    const float* hd = (const float*)d_in[1];
    const float* xg = (const float*)d_in[2];
    const float* hg = (const float*)d_in[3];
    const int*  src = (const int*)d_in[4];
    const int*  dst = (const int*)d_in[5];

    int n_d     = in_sizes[0] / FD;
    int n_g     = in_sizes[2] / FD;
    int n_edges = in_sizes[4];

    // ws: fd = n_d rows of 128 halves (256 B), then fg = n_g rows.
    __half2* fd = (__half2*)d_ws;
    __half2* fg = fd + (size_t)n_d * FD;
    float*  out = (float*)d_out;

    int total_nodes = n_d + n_g;
    int nb1 = (total_nodes * 64 + 255) / 256;   // one wave per node
    pack_kernel<<<nb1, 256, 0, stream>>>(xd, hd, xg, hg, fd, fg, n_d, n_g);

    int nb2 = (int)(((long long)n_edges * 16 + 255) / 256);  // 16 lanes per edge
    edge_kernel<<<nb2, 256, 0, stream>>>((const float4*)fd, (const float4*)fg,
                                         src, dst, out, n_edges);
}

// Round 3
// 167.247 us; speedup vs baseline: 2.2072x; 1.3866x over previous
//
#include <hip/hip_runtime.h>

// Per-edge cosine similarity. Node rows pre-normalized and quantized to int8
// with a per-row fp32 scale -> 128 B/row = exactly ONE 128 B cache line.
// Edge gather = 2 lines/edge (the structural floor for 2 random row reads).
//
// Pack: 16 lanes/node. lane j handles x[4j..4j+3] and h[4j..4j+3].
//   Row byte layout: int 2j = q(x[4j..4j+3]), int 2j+1 = q(h[4j..4j+3]).
//   Same layout for both tables -> elementwise products align in the dot.
// Edge: 8 lanes/edge, each lane one int4 (16 int8) per row, 4x sdot4,
//   3-step shuffle reduce, out = idot * s_d[src] * s_g[dst].

#define FD 64

__device__ __forceinline__ int q8pack(float v0, float v1, float v2, float v3, float inv) {
    float a0 = fminf(fmaxf(v0 * inv, -127.f), 127.f);
    float a1 = fminf(fmaxf(v1 * inv, -127.f), 127.f);
    float a2 = fminf(fmaxf(v2 * inv, -127.f), 127.f);
    float a3 = fminf(fmaxf(v3 * inv, -127.f), 127.f);
    int q0 = ((int)rintf(a0)) & 0xff;
    int q1 = ((int)rintf(a1)) & 0xff;
    int q2 = ((int)rintf(a2)) & 0xff;
    int q3 = ((int)rintf(a3)) & 0xff;
    return q0 | (q1 << 8) | (q2 << 16) | (q3 << 24);
}

__global__ void pack_kernel(const float4* __restrict__ xd, const float4* __restrict__ hd,
                            const float4* __restrict__ xg, const float4* __restrict__ hg,
                            int2* __restrict__ fd, int2* __restrict__ fg,
                            float* __restrict__ sd, float* __restrict__ sg,
                            int n_d, int n_g)
{
    int tid  = (int)(blockIdx.x * blockDim.x + threadIdx.x);
    int node = tid >> 4;
    int lane = threadIdx.x & 15;
    int total = n_d + n_g;
    if (node >= total) return;

    const float4* x; const float4* h; int2* o; float* s; int n;
    if (node < n_d) { x = xd; h = hd; o = fd; s = sd; n = node; }
    else            { x = xg; h = hg; o = fg; s = sg; n = node - n_d; }

    float4 a = x[(size_t)n * 16 + lane];   // x[4*lane .. 4*lane+3]
    float4 b = h[(size_t)n * 16 + lane];

    float ss = a.x*a.x + a.y*a.y + a.z*a.z + a.w*a.w
             + b.x*b.x + b.y*b.y + b.z*b.z + b.w*b.w;
    #pragma unroll
    for (int m = 8; m >= 1; m >>= 1) ss += __shfl_xor(ss, m);
    float r = rsqrtf(ss);

    a.x *= r; a.y *= r; a.z *= r; a.w *= r;
    b.x *= r; b.y *= r; b.z *= r; b.w *= r;

    float mx = fmaxf(fmaxf(fmaxf(fabsf(a.x), fabsf(a.y)), fmaxf(fabsf(a.z), fabsf(a.w))),
                     fmaxf(fmaxf(fabsf(b.x), fabsf(b.y)), fmaxf(fabsf(b.z), fabsf(b.w))));
    #pragma unroll
    for (int m = 8; m >= 1; m >>= 1) mx = fmaxf(mx, __shfl_xor(mx, m));

    float inv = 127.0f / mx;          // dequant scale = mx/127

    int2 w;
    w.x = q8pack(a.x, a.y, a.z, a.w, inv);
    w.y = q8pack(b.x, b.y, b.z, b.w, inv);
    o[(size_t)n * 16 + lane] = w;     // row = 32 ints = 16 int2, 128 B contiguous

    if (lane == 0) s[n] = mx * (1.0f / 127.0f);
}

__device__ __forceinline__ int dot4(int a, int b, int c) {
    return __builtin_amdgcn_sdot4(a, b, c, false);   // v_dot4_i32_i8 (gfx906+)
}

// 8 lanes per edge; row = 8 int4 (128 B).
__global__ void edge_kernel(const int4* __restrict__ fd, const int4* __restrict__ fg,
                            const float* __restrict__ sd, const float* __restrict__ sg,
                            const int* __restrict__ src, const int* __restrict__ dst,
                            float* __restrict__ out, int n_edges)
{
    int tid  = (int)(blockIdx.x * blockDim.x + threadIdx.x);
    int lane = threadIdx.x & 7;
    int e    = tid >> 3;
    if (e >= n_edges) return;

    int s = src[e];
    int d = dst[e];

    int4 a = fd[(size_t)s * 8 + lane];
    int4 b = fg[(size_t)d * 8 + lane];

    int acc = dot4(a.x, b.x, dot4(a.y, b.y, dot4(a.z, b.z, dot4(a.w, b.w, 0))));

    acc += __shfl_xor(acc, 4);
    acc += __shfl_xor(acc, 2);
    acc += __shfl_xor(acc, 1);

    if (lane == 0) out[e] = (float)acc * sd[s] * sg[d];
}

extern "C" void kernel_launch(void* const* d_in, const int* in_sizes, int n_in,
                              void* d_out, int out_size, void* d_ws, size_t ws_size,
                              hipStream_t stream) {
    const float* xd = (const float*)d_in[0];
    const float* hd = (const float*)d_in[1];
    const float* xg = (const float*)d_in[2];
    const float* hg = (const float*)d_in[3];
    const int*  src = (const int*)d_in[4];
    const int*  dst = (const int*)d_in[5];

    int n_d     = in_sizes[0] / FD;
    int n_g     = in_sizes[2] / FD;
    int n_edges = in_sizes[4];

    // ws layout: fd rows (n_d*128 B), fg rows (n_g*128 B), sd, sg.
    char* ws = (char*)d_ws;
    int2*  fd = (int2*)ws;                       ws += (size_t)n_d * 128;
    int2*  fg = (int2*)ws;                       ws += (size_t)n_g * 128;
    float* sd = (float*)ws;                      ws += (size_t)n_d * sizeof(float);
    float* sg = (float*)ws;
    float* out = (float*)d_out;

    int total_nodes = n_d + n_g;
    int nb1 = (total_nodes * 16 + 255) / 256;
    pack_kernel<<<nb1, 256, 0, stream>>>((const float4*)xd, (const float4*)hd,
                                         (const float4*)xg, (const float4*)hg,
                                         fd, fg, sd, sg, n_d, n_g);

    int nb2 = (int)(((long long)n_edges * 8 + 255) / 256);
    edge_kernel<<<nb2, 256, 0, stream>>>((const int4*)fd, (const int4*)fg,
                                         sd, sg, src, dst, out, n_edges);
}